// Round 18
// baseline (92.156 us; speedup 1.0000x reference)
//
#include <hip/hip_runtime.h>
#include <hip/hip_fp16.h>
#include <stdint.h>
#include <math.h>

#define B 4096
#define D 512
#define NIMG_SHIFT 3

#define BM 128
#define BN 128
#define NKS 8              // K = 512, BK = 64 f16 (128B)
#define NCH (B / BN)       // 32 col chunks

typedef _Float16 f16x8 __attribute__((ext_vector_type(8)));
typedef float f32x4 __attribute__((ext_vector_type(4)));

#define LDSPTR(p) ((__attribute__((address_space(3))) void*)(p))
#define GLPTR(p)  ((const __attribute__((address_space(1))) void*)(p))

// -------- static device workspace (fully rewritten every call) ----
__device__ __half   Q2h[(size_t)B * D];      // f16 copy of Q (unscaled)
__device__ __half   G2h[(size_t)B * D];
__device__ float    nqd[B], ngd[B], psd[B], spd[B];
__device__ uint32_t bKeyd[NCH * B];          // [chunk][row]
__device__ float    bDnd[NCH * B];
__device__ float    mDnd[NCH * B];
__device__ float    partd[B / 8];

// ---------------- threefry2x32 ----------------
__host__ __device__ inline void tf2x32(uint32_t k0, uint32_t k1,
                                       uint32_t x0, uint32_t x1,
                                       uint32_t& y0, uint32_t& y1) {
  const uint32_t ks2 = k0 ^ k1 ^ 0x1BD11BDAu;
  uint32_t v0 = x0 + k0, v1 = x1 + k1;
#define RR(r) { v0 += v1; v1 = (v1 << (r)) | (v1 >> (32 - (r))); v1 ^= v0; }
  RR(13) RR(15) RR(26) RR(6)   v0 += k1;  v1 += ks2 + 1u;
  RR(17) RR(29) RR(16) RR(24)  v0 += ks2; v1 += k0 + 2u;
  RR(13) RR(15) RR(26) RR(6)   v0 += k0;  v1 += k1 + 3u;
  RR(17) RR(29) RR(16) RR(24)  v0 += k1;  v1 += ks2 + 4u;
  RR(13) RR(15) RR(26) RR(6)   v0 += ks2; v1 += k0 + 5u;
#undef RR
  y0 = v0; y1 = v1;
}

__device__ inline uint32_t draw_bits(uint32_t key0, uint32_t key1, uint32_t flat) {
  uint32_t y0, y1;
  tf2x32(key0, key1, 0u, flat, y0, y1);
  return y1;
}

__device__ inline float gumbel_from_bits(uint32_t bits) {
  float f = __uint_as_float((bits >> 9) | 0x3f800000u) - 1.0f;
  float u = (f == 0.0f) ? 1.17549435e-38f : f;
  return -logf(-logf(u));
}

// ---- Kernel 1: fused fp32 stage -> f16 copy + norms + positive sampling ----
__global__ __launch_bounds__(256) void cvp_k(const float* __restrict__ Q,
                                             const float* __restrict__ G,
                                             uint32_t kp0, uint32_t kp1) {
  __shared__ float Qs[8][D];
  __shared__ float Gs[8][D];
  __shared__ float dots[8][8];
  __shared__ float nql[8], ngl[8];
  const int t = threadIdx.x;
  const int rbase = blockIdx.x * 8;
  // stage fp32 rows
#pragma unroll
  for (int s = 0; s < 4; s++) {
    int idx = t + 256 * s;
    int rr = idx >> 7;
    int kk = idx & 127;
    ((float4*)&Qs[rr][0])[kk] = ((const float4*)(Q + (size_t)(rbase + rr) * D))[kk];
    ((float4*)&Gs[rr][0])[kk] = ((const float4*)(G + (size_t)(rbase + rr) * D))[kk];
  }
  __syncthreads();
  // f16 copies
#pragma unroll
  for (int s = 0; s < 4; s++) {
    int idx = t + 256 * s;
    int rr = idx >> 7;
    int kk = idx & 127;
    float4 vq = ((const float4*)&Qs[rr][0])[kk];
    float4 vg = ((const float4*)&Gs[rr][0])[kk];
    __half hq[4] __attribute__((aligned(8)));
    __half hg[4] __attribute__((aligned(8)));
    const float* pq = (const float*)&vq;
    const float* pg = (const float*)&vg;
#pragma unroll
    for (int j = 0; j < 4; j++) { hq[j] = __float2half(pq[j]); hg[j] = __float2half(pg[j]); }
    *(uint2*)(Q2h + (size_t)(rbase + rr) * D + kk * 4) = *(const uint2*)hq;
    *(uint2*)(G2h + (size_t)(rbase + rr) * D + kk * 4) = *(const uint2*)hg;
  }
  // norms (per-row order bit-identical to the original cvtn_k)
  {
    const int wave = t >> 6, lane = t & 63;
#pragma unroll
    for (int rr2 = 0; rr2 < 4; rr2++) {
      const int rowid = wave * 4 + rr2;
      const float* src = (rowid < 8) ? &Qs[rowid][0] : &Gs[rowid - 8][0];
      float ssq = 0.0f;
#pragma unroll
      for (int i = 0; i < 2; i++) {
        float4 v = ((const float4*)src)[lane + 64 * i];
        ssq += v.x * v.x + v.y * v.y + v.z * v.z + v.w * v.w;
      }
#pragma unroll
      for (int off = 32; off; off >>= 1) ssq += __shfl_xor(ssq, off, 64);
      if (lane == 0) {
        if (rowid < 8) { nqd[rbase + rowid] = ssq; nql[rowid] = ssq; }
        else           { ngd[rbase + rowid - 8] = ssq; ngl[rowid - 8] = ssq; }
      }
    }
  }
  __syncthreads();
  // 8x8 dots
  {
    int p = t >> 2;
    int part = t & 3;
    int i = p >> 3, j = p & 7;
    float s = 0.0f;
    int k0 = part * 128;
    for (int k = k0; k < k0 + 128; k++) s += Qs[i][k] * Gs[j][k];
    s += __shfl_xor(s, 1, 64);
    s += __shfl_xor(s, 2, 64);
    if (part == 0) dots[i][j] = s;
  }
  __syncthreads();
  if (t < 8) {
    int i = t;
    int r = rbase + i;
    float nqr = nql[i];
    float best = -INFINITY;
    float bdp = 0.0f;
#pragma unroll
    for (int j = 0; j < 8; j++) {
      if (j == i) continue;
      int c = rbase + j;
      float dp = fmaxf(nqr + ngl[j] - 2.0f * dots[i][j], 1e-8f);
      uint32_t bits = draw_bits(kp0, kp1, (uint32_t)(r * B + c));
      float logit = logf(dp) + gumbel_from_bits(bits);
      if (logit > best) { best = logit; bdp = dp; }
    }
    psd[r] = bdp;
    spd[r] = sqrtf(bdp);
  }
}

// ---- Kernel 3: f16 MFMA GEMM, 8 waves, dbuf + counted vmcnt, keys in-loop ----
// Epilogue (only change vs round 17): packed pk = (key<<7)|(127-off) reduce —
// max(pk) = (key desc, col asc), bit-exact JAX first-index tie-break; one
// fewer shuffle + fewer selects per reduce step; no extra K-loop live state.
__global__ __launch_bounds__(512) void neg_k(uint32_t kn0, uint32_t kn1) {
  __shared__ char lds[65536] __attribute__((aligned(16)));
  const int t = threadIdx.x;
  const int l = t & 63;
  const int w = t >> 6;          // 0..7
  const int wr = w >> 1;         // 0..3 (32-row slabs)
  const int wc = w & 1;          // 0..1 (64-col halves)
  const int lane16 = l & 15, g16 = l >> 4;
  const int r0 = blockIdx.y * BM;
  const int c0 = blockIdx.x * BN;

  f32x4 acc[2][4];
#pragma unroll
  for (int mi = 0; mi < 2; mi++)
#pragma unroll
    for (int nj = 0; nj < 4; nj++) acc[mi][nj] = (f32x4){0.f, 0.f, 0.f, 0.f};

  const char* qbase = (const char*)Q2h + (size_t)r0 * 1024;
  const char* gbase = (const char*)G2h + (size_t)c0 * 1024;

  // staging: linear LDS dest li[s]; pre-swizzled global source.
  // swizzle: byte ^= ((row&7)<<4), row = byte>>7 (128B rows) — involution.
  int li[2], rc[2];
#pragma unroll
  for (int s = 0; s < 2; s++) {
    li[s] = t * 16 + s * 8192;
    const int aa = li[s] ^ (((li[s] >> 7) & 7) << 4);
    rc[s] = (aa >> 7) * 1024 + (aa & 127);   // global row byte-offset + col
  }

  // fragment read offsets (swizzled). kk=1 is logical +64 (bit 6): since the
  // swizzle XOR covers bits 4-6, f(a+64) = f(a) ^ 64 (XOR, not add).
  int offA[2], offA2[2], offB[4], offB2[4];
#pragma unroll
  for (int i = 0; i < 2; i++) {
    const int a = (wr * 32 + i * 16 + lane16) * 128 + g16 * 16;
    offA[i] = a ^ (((a >> 7) & 7) << 4);
    offA2[i] = offA[i] ^ 64;
  }
#pragma unroll
  for (int i = 0; i < 4; i++) {
    const int b = (wc * 64 + i * 16 + lane16) * 128 + g16 * 16;
    offB[i] = b ^ (((b >> 7) & 7) << 4);
    offB2[i] = offB[i] ^ 64;
  }

  uint32_t keys[32];   // statically indexed only (rule #20)

#define KEYS4(K) do {                                                          \
    const int mi_ = (K) >> 2, q_ = (K) & 3;                                    \
    const uint32_t rr_ = (uint32_t)(r0 + wr * 32 + mi_ * 16 + g16 * 4 + q_);   \
    _Pragma("unroll")                                                          \
    for (int nj = 0; nj < 4; nj++) {                                           \
      const uint32_t cc_ = (uint32_t)(c0 + wc * 64 + nj * 16 + lane16);        \
      keys[(K) * 4 + nj] = (draw_bits(kn0, kn1, (rr_ << 12) | cc_) >> 9) + 1u; \
    }                                                                          \
  } while (0)

#define GLDS(SRC, DOFF) __builtin_amdgcn_global_load_lds(GLPTR(SRC), LDSPTR(lds + (DOFF)), 16, 0, 0)

#define STAGE(BUF, KS) do {                                            \
    _Pragma("unroll")                                                  \
    for (int s = 0; s < 2; s++) {                                      \
      GLDS(qbase + rc[s] + (KS) * 128, (BUF) * 32768 + li[s]);         \
      GLDS(gbase + rc[s] + (KS) * 128, (BUF) * 32768 + 16384 + li[s]); \
    }                                                                  \
  } while (0)

#define COMPUTE(BUF) do {                                                    \
    const char* lsrc = lds + (BUF) * 32768;                                  \
    f16x8 av[2][2], bv[4][2];                                                \
    _Pragma("unroll")                                                        \
    for (int i = 0; i < 2; i++) {                                            \
      av[i][0] = *(const f16x8*)(lsrc + offA[i]);                            \
      av[i][1] = *(const f16x8*)(lsrc + offA2[i]);                           \
    }                                                                        \
    _Pragma("unroll")                                                        \
    for (int i = 0; i < 4; i++) {                                            \
      bv[i][0] = *(const f16x8*)(lsrc + 16384 + offB[i]);                    \
      bv[i][1] = *(const f16x8*)(lsrc + 16384 + offB2[i]);                   \
    }                                                                        \
    _Pragma("unroll")                                                        \
    for (int kk = 0; kk < 2; kk++)                                           \
      _Pragma("unroll")                                                      \
      for (int nj = 0; nj < 4; nj++)                                         \
        _Pragma("unroll")                                                    \
        for (int mi = 0; mi < 2; mi++)                                       \
          acc[mi][nj] = __builtin_amdgcn_mfma_f32_16x16x32_f16(av[mi][kk], bv[nj][kk], acc[mi][nj], 0, 0, 0); \
  } while (0)

#define VM4  asm volatile("s_waitcnt vmcnt(4)" ::: "memory")
#define VM0  asm volatile("s_waitcnt vmcnt(0)" ::: "memory")
#define BAR  __builtin_amdgcn_s_barrier()

  STAGE(0, 0); KEYS4(0);
  STAGE(1, 1); KEYS4(1); VM4; BAR; COMPUTE(0); BAR;
  STAGE(0, 2); KEYS4(2); VM4; BAR; COMPUTE(1); BAR;
  STAGE(1, 3); KEYS4(3); VM4; BAR; COMPUTE(0); BAR;
  STAGE(0, 4); KEYS4(4); VM4; BAR; COMPUTE(1); BAR;
  STAGE(1, 5); KEYS4(5); VM4; BAR; COMPUTE(0); BAR;
  STAGE(0, 6); KEYS4(6); VM4; BAR; COMPUTE(1); BAR;
  STAGE(1, 7); KEYS4(7); VM4; BAR; COMPUTE(0); BAR;
               VM0; BAR; COMPUTE(1);
#undef STAGE
#undef COMPUTE
#undef GLDS
#undef VM4
#undef VM0
#undef BAR
#undef KEYS4
  __syncthreads();

  // epilogue partial arrays overlaid on LDS: [2 wc][128 rows]
  uint32_t* pKey = (uint32_t*)lds;
  float*    pD   = (float*)(pKey + 256);
  float*    pM   = pD + 256;

  // batched uniforms (computed here, not across the K-loop)
  float ngv4[4];
  int cg4[4], io4[4];
#pragma unroll
  for (int nj = 0; nj < 4; nj++) {
    const int off = wc * 64 + nj * 16 + lane16;   // in-chunk column, 0..127
    ngv4[nj] = ngd[c0 + off];
    cg4[nj] = (c0 + off) >> NIMG_SHIFT;
    io4[nj] = 127 - off;
  }

#pragma unroll
  for (int mi = 0; mi < 2; mi++) {
    const int rbase = r0 + wr * 32 + mi * 16 + g16 * 4;
    const float4 nq4 = *(const float4*)(nqd + rbase);
    const float4 ps4 = *(const float4*)(psd + rbase);
#pragma unroll
    for (int q = 0; q < 4; q++) {
      const int rr = wr * 32 + mi * 16 + g16 * 4 + q;
      const int rg = (rbase + q) >> NIMG_SHIFT;
      const float nqv = ((const float*)&nq4)[q];
      const float thr = ((const float*)&ps4)[q] + 1e-4f;
      uint32_t bPk = 0u, mC = 0xFFFFFFFFu;
      float bD = 0.0f, mD = INFINITY;
#pragma unroll
      for (int nj = 0; nj < 4; nj++) {   // pk strictly ordered: key desc, col asc
        const float dv = fmaxf(nqv + ngv4[nj] - 2.0f * acc[mi][nj][q], 1e-8f);
        const float dn = (cg4[nj] == rg) ? 1e25f : dv;
        if (dn < mD) { mD = dn; mC = (uint32_t)(127 - io4[nj]); }
        const uint32_t key = (dn < thr) ? keys[mi * 16 + q * 4 + nj] : 0u;
        const uint32_t pk = (key << 7) | (uint32_t)io4[nj];
        if (pk > bPk) { bPk = pk; bD = dn; }
      }
#pragma unroll
      for (int off = 8; off >= 1; off >>= 1) {
        const uint32_t pkO = __shfl_xor(bPk, off, 64);
        const float dO = __shfl_xor(bD, off, 64);
        if (pkO > bPk) { bPk = pkO; bD = dO; }   // pk distinct across lanes
        const float mdO = __shfl_xor(mD, off, 64);
        const uint32_t mcO = __shfl_xor(mC, off, 64);
        if (mdO < mD || (mdO == mD && mcO < mC)) { mD = mdO; mC = mcO; }
      }
      if (lane16 == 0) {
        const int idx = wc * 128 + rr;
        pKey[idx] = bPk >> 7;   // pure key; 0 == "no candidate" (argmin fallback)
        pD[idx] = bD; pM[idx] = mD;
      }
    }
  }
  __syncthreads();
  if (t < 128) {
    // combine column halves; ties resolve to half 0 (smaller columns) = first index
    const uint32_t k0 = pKey[t], k1 = pKey[t + 128];
    const float d0 = pD[t], d1 = pD[t + 128];
    const uint32_t bk = (k1 > k0) ? k1 : k0;
    const float bd = (k1 > k0) ? d1 : d0;
    const float m0 = pM[t], m1 = pM[t + 128];
    const float md = (m1 < m0) ? m1 : m0;
    const int p = blockIdx.x * B + (r0 + t);   // [chunk][row]: coalesced
    bKeyd[p] = bk; bDnd[p] = bd; mDnd[p] = md;
  }
}

// ---------------- Kernel 4a: per-row chunk combine + softplus, block partial --
__global__ __launch_bounds__(256) void fin1_k() {
  __shared__ float red[8];
  const int t = threadIdx.x;
  const int lrow = t >> 5;              // 0..7 rows per block
  const int ch = t & 31;                // chunk index (NCH=32)
  const int r = blockIdx.x * 8 + lrow;
  const int p = ch * B + r;             // [chunk][row]
  uint32_t bk = bKeyd[p];
  uint32_t bch = (uint32_t)ch;
  float bd = bDnd[p];
  float md = mDnd[p];
  uint32_t mch = (uint32_t)ch;
#pragma unroll
  for (int off = 16; off >= 1; off >>= 1) {
    const uint32_t kO = __shfl_xor(bk, off, 64);
    const uint32_t cO = __shfl_xor(bch, off, 64);
    const float dO = __shfl_xor(bd, off, 64);
    if (kO > bk || (kO == bk && cO < bch)) { bk = kO; bch = cO; bd = dO; }
    const float mO = __shfl_xor(md, off, 64);
    const uint32_t mcO = __shfl_xor(mch, off, 64);
    if (mO < md || (mO == md && mcO < mch)) { md = mO; mch = mcO; }
  }
  if (ch == 0) {
    const float dn = (bk != 0u) ? bd : md;
    const float x = 1e-4f + spd[r] - sqrtf(dn);
    red[lrow] = fmaxf(x, 0.0f) + log1pf(expf(-fabsf(x)));
  }
  __syncthreads();
  if (t == 0) {
    float s = 0.0f;
#pragma unroll
    for (int i = 0; i < 8; i++) s += red[i];
    partd[blockIdx.x] = s;
  }
}

// ---------------- Kernel 4b: sum 512 partials, mean ----------------
__global__ __launch_bounds__(256) void fin2_k(float* __restrict__ out) {
  __shared__ float red[256];
  const int t = threadIdx.x;
  red[t] = partd[t] + partd[t + 256];
  __syncthreads();
#pragma unroll
  for (int s = 128; s; s >>= 1) {
    if (t < s) red[t] += red[t + s];
    __syncthreads();
  }
  if (t == 0) out[0] = red[0] * (1.0f / (float)B);
}

extern "C" void kernel_launch(void* const* d_in, const int* in_sizes, int n_in,
                              void* d_out, int out_size, void* d_ws, size_t ws_size,
                              hipStream_t stream) {
  (void)in_sizes; (void)n_in; (void)out_size; (void)d_ws; (void)ws_size;
  const float* Q = (const float*)d_in[0];
  const float* G = (const float*)d_in[1];
  float* out = (float*)d_out;

  uint32_t kp0, kp1, kn0, kn1;
  tf2x32(0u, 42u, 0u, 0u, kp0, kp1);
  tf2x32(0u, 42u, 0u, 1u, kn0, kn1);

  hipLaunchKernelGGL(cvp_k, dim3(B / 8), dim3(256), 0, stream, Q, G, kp0, kp1);
  hipLaunchKernelGGL(neg_k, dim3(B / BN, B / BM), dim3(512), 0, stream, kn0, kn1);
  hipLaunchKernelGGL(fin1_k, dim3(B / 8), dim3(256), 0, stream);
  hipLaunchKernelGGL(fin2_k, dim3(1), dim3(256), 0, stream, out);
}

// Round 19
// 83.118 us; speedup vs baseline: 1.1087x; 1.1087x over previous
//
#include <hip/hip_runtime.h>
#include <hip/hip_fp16.h>
#include <stdint.h>
#include <math.h>

#define B 4096
#define D 512
#define NIMG_SHIFT 3

#define BM 128
#define BN 128
#define NKS 8              // K = 512, BK = 64 f16 (128B)
#define NCH (B / BN)       // 32 col chunks

typedef _Float16 f16x8 __attribute__((ext_vector_type(8)));
typedef float f32x4 __attribute__((ext_vector_type(4)));

#define LDSPTR(p) ((__attribute__((address_space(3))) void*)(p))
#define GLPTR(p)  ((const __attribute__((address_space(1))) void*)(p))

// -------- static device workspace (fully rewritten every call) ----
__device__ __half   Q2h[(size_t)B * D];      // f16 copy of Q (unscaled)
__device__ __half   G2h[(size_t)B * D];
__device__ float    nqd[B], ngd[B], psd[B], spd[B];
__device__ uint32_t bKeyd[NCH * B];          // [chunk][row]
__device__ float    bDnd[NCH * B];
__device__ float    mDnd[NCH * B];
__device__ float    partd[B / 8];

// ---------------- threefry2x32 ----------------
__host__ __device__ inline void tf2x32(uint32_t k0, uint32_t k1,
                                       uint32_t x0, uint32_t x1,
                                       uint32_t& y0, uint32_t& y1) {
  const uint32_t ks2 = k0 ^ k1 ^ 0x1BD11BDAu;
  uint32_t v0 = x0 + k0, v1 = x1 + k1;
#define RR(r) { v0 += v1; v1 = (v1 << (r)) | (v1 >> (32 - (r))); v1 ^= v0; }
  RR(13) RR(15) RR(26) RR(6)   v0 += k1;  v1 += ks2 + 1u;
  RR(17) RR(29) RR(16) RR(24)  v0 += ks2; v1 += k0 + 2u;
  RR(13) RR(15) RR(26) RR(6)   v0 += k0;  v1 += k1 + 3u;
  RR(17) RR(29) RR(16) RR(24)  v0 += k1;  v1 += ks2 + 4u;
  RR(13) RR(15) RR(26) RR(6)   v0 += ks2; v1 += k0 + 5u;
#undef RR
  y0 = v0; y1 = v1;
}

__device__ inline uint32_t draw_bits(uint32_t key0, uint32_t key1, uint32_t flat) {
  uint32_t y0, y1;
  tf2x32(key0, key1, 0u, flat, y0, y1);
  return y1;
}

__device__ inline float gumbel_from_bits(uint32_t bits) {
  float f = __uint_as_float((bits >> 9) | 0x3f800000u) - 1.0f;
  float u = (f == 0.0f) ? 1.17549435e-38f : f;
  return -logf(-logf(u));
}

// ---- Kernel 1: fused fp32 stage -> f16 copy + norms + positive sampling ----
__global__ __launch_bounds__(256) void cvp_k(const float* __restrict__ Q,
                                             const float* __restrict__ G,
                                             uint32_t kp0, uint32_t kp1) {
  __shared__ float Qs[8][D];
  __shared__ float Gs[8][D];
  __shared__ float dots[8][8];
  __shared__ float nql[8], ngl[8];
  const int t = threadIdx.x;
  const int rbase = blockIdx.x * 8;
  // stage fp32 rows
#pragma unroll
  for (int s = 0; s < 4; s++) {
    int idx = t + 256 * s;
    int rr = idx >> 7;
    int kk = idx & 127;
    ((float4*)&Qs[rr][0])[kk] = ((const float4*)(Q + (size_t)(rbase + rr) * D))[kk];
    ((float4*)&Gs[rr][0])[kk] = ((const float4*)(G + (size_t)(rbase + rr) * D))[kk];
  }
  __syncthreads();
  // f16 copies
#pragma unroll
  for (int s = 0; s < 4; s++) {
    int idx = t + 256 * s;
    int rr = idx >> 7;
    int kk = idx & 127;
    float4 vq = ((const float4*)&Qs[rr][0])[kk];
    float4 vg = ((const float4*)&Gs[rr][0])[kk];
    __half hq[4] __attribute__((aligned(8)));
    __half hg[4] __attribute__((aligned(8)));
    const float* pq = (const float*)&vq;
    const float* pg = (const float*)&vg;
#pragma unroll
    for (int j = 0; j < 4; j++) { hq[j] = __float2half(pq[j]); hg[j] = __float2half(pg[j]); }
    *(uint2*)(Q2h + (size_t)(rbase + rr) * D + kk * 4) = *(const uint2*)hq;
    *(uint2*)(G2h + (size_t)(rbase + rr) * D + kk * 4) = *(const uint2*)hg;
  }
  // norms (per-row order bit-identical to the original cvtn_k)
  {
    const int wave = t >> 6, lane = t & 63;
#pragma unroll
    for (int rr2 = 0; rr2 < 4; rr2++) {
      const int rowid = wave * 4 + rr2;
      const float* src = (rowid < 8) ? &Qs[rowid][0] : &Gs[rowid - 8][0];
      float ssq = 0.0f;
#pragma unroll
      for (int i = 0; i < 2; i++) {
        float4 v = ((const float4*)src)[lane + 64 * i];
        ssq += v.x * v.x + v.y * v.y + v.z * v.z + v.w * v.w;
      }
#pragma unroll
      for (int off = 32; off; off >>= 1) ssq += __shfl_xor(ssq, off, 64);
      if (lane == 0) {
        if (rowid < 8) { nqd[rbase + rowid] = ssq; nql[rowid] = ssq; }
        else           { ngd[rbase + rowid - 8] = ssq; ngl[rowid - 8] = ssq; }
      }
    }
  }
  __syncthreads();
  // 8x8 dots
  {
    int p = t >> 2;
    int part = t & 3;
    int i = p >> 3, j = p & 7;
    float s = 0.0f;
    int k0 = part * 128;
    for (int k = k0; k < k0 + 128; k++) s += Qs[i][k] * Gs[j][k];
    s += __shfl_xor(s, 1, 64);
    s += __shfl_xor(s, 2, 64);
    if (part == 0) dots[i][j] = s;
  }
  __syncthreads();
  if (t < 8) {
    int i = t;
    int r = rbase + i;
    float nqr = nql[i];
    float best = -INFINITY;
    float bdp = 0.0f;
#pragma unroll
    for (int j = 0; j < 8; j++) {
      if (j == i) continue;
      int c = rbase + j;
      float dp = fmaxf(nqr + ngl[j] - 2.0f * dots[i][j], 1e-8f);
      uint32_t bits = draw_bits(kp0, kp1, (uint32_t)(r * B + c));
      float logit = logf(dp) + gumbel_from_bits(bits);
      if (logit > best) { best = logit; bdp = dp; }
    }
    psd[r] = bdp;
    spd[r] = sqrtf(bdp);
  }
}

// ---- Kernel 3: f16 MFMA GEMM, 8 waves, dbuf + counted vmcnt, keys in-loop ----
// LDS: buf0 {A@0, B@16384}, buf1 {A@32768, B@49152} — 64KB total.
// Per K-step: STAGE(next) -> KEYS4 (threefry under load shadow) -> vmcnt(4)
// -> s_barrier -> COMPUTE(cur) -> s_barrier. Epilogue is threefry-free.
// NOTE: this kernel sits exactly at the VGPR=64 occupancy bucket; any epilogue
// change adding live registers crosses it and halves occupancy (r16/r18).
__global__ __launch_bounds__(512) void neg_k(uint32_t kn0, uint32_t kn1) {
  __shared__ char lds[65536] __attribute__((aligned(16)));
  const int t = threadIdx.x;
  const int l = t & 63;
  const int w = t >> 6;          // 0..7
  const int wr = w >> 1;         // 0..3 (32-row slabs)
  const int wc = w & 1;          // 0..1 (64-col halves)
  const int lane16 = l & 15, g16 = l >> 4;
  const int r0 = blockIdx.y * BM;
  const int c0 = blockIdx.x * BN;

  f32x4 acc[2][4];
#pragma unroll
  for (int mi = 0; mi < 2; mi++)
#pragma unroll
    for (int nj = 0; nj < 4; nj++) acc[mi][nj] = (f32x4){0.f, 0.f, 0.f, 0.f};

  const char* qbase = (const char*)Q2h + (size_t)r0 * 1024;
  const char* gbase = (const char*)G2h + (size_t)c0 * 1024;

  // staging: linear LDS dest li[s]; pre-swizzled global source.
  // swizzle: byte ^= ((row&7)<<4), row = byte>>7 (128B rows) — involution.
  int li[2], rc[2];
#pragma unroll
  for (int s = 0; s < 2; s++) {
    li[s] = t * 16 + s * 8192;
    const int aa = li[s] ^ (((li[s] >> 7) & 7) << 4);
    rc[s] = (aa >> 7) * 1024 + (aa & 127);   // global row byte-offset + col
  }

  // fragment read offsets (swizzled). kk=1 is logical +64 (bit 6): since the
  // swizzle XOR covers bits 4-6, f(a+64) = f(a) ^ 64 (XOR, not add).
  int offA[2], offA2[2], offB[4], offB2[4];
#pragma unroll
  for (int i = 0; i < 2; i++) {
    const int a = (wr * 32 + i * 16 + lane16) * 128 + g16 * 16;
    offA[i] = a ^ (((a >> 7) & 7) << 4);
    offA2[i] = offA[i] ^ 64;
  }
#pragma unroll
  for (int i = 0; i < 4; i++) {
    const int b = (wc * 64 + i * 16 + lane16) * 128 + g16 * 16;
    offB[i] = b ^ (((b >> 7) & 7) << 4);
    offB2[i] = offB[i] ^ 64;
  }

  uint32_t keys[32];   // statically indexed only (rule #20)

#define KEYS4(K) do {                                                          \
    const int mi_ = (K) >> 2, q_ = (K) & 3;                                    \
    const uint32_t rr_ = (uint32_t)(r0 + wr * 32 + mi_ * 16 + g16 * 4 + q_);   \
    _Pragma("unroll")                                                          \
    for (int nj = 0; nj < 4; nj++) {                                           \
      const uint32_t cc_ = (uint32_t)(c0 + wc * 64 + nj * 16 + lane16);        \
      keys[(K) * 4 + nj] = (draw_bits(kn0, kn1, (rr_ << 12) | cc_) >> 9) + 1u; \
    }                                                                          \
  } while (0)

#define GLDS(SRC, DOFF) __builtin_amdgcn_global_load_lds(GLPTR(SRC), LDSPTR(lds + (DOFF)), 16, 0, 0)

#define STAGE(BUF, KS) do {                                            \
    _Pragma("unroll")                                                  \
    for (int s = 0; s < 2; s++) {                                      \
      GLDS(qbase + rc[s] + (KS) * 128, (BUF) * 32768 + li[s]);         \
      GLDS(gbase + rc[s] + (KS) * 128, (BUF) * 32768 + 16384 + li[s]); \
    }                                                                  \
  } while (0)

#define COMPUTE(BUF) do {                                                    \
    const char* lsrc = lds + (BUF) * 32768;                                  \
    f16x8 av[2][2], bv[4][2];                                                \
    _Pragma("unroll")                                                        \
    for (int i = 0; i < 2; i++) {                                            \
      av[i][0] = *(const f16x8*)(lsrc + offA[i]);                            \
      av[i][1] = *(const f16x8*)(lsrc + offA2[i]);                           \
    }                                                                        \
    _Pragma("unroll")                                                        \
    for (int i = 0; i < 4; i++) {                                            \
      bv[i][0] = *(const f16x8*)(lsrc + 16384 + offB[i]);                    \
      bv[i][1] = *(const f16x8*)(lsrc + 16384 + offB2[i]);                   \
    }                                                                        \
    _Pragma("unroll")                                                        \
    for (int kk = 0; kk < 2; kk++)                                           \
      _Pragma("unroll")                                                      \
      for (int nj = 0; nj < 4; nj++)                                         \
        _Pragma("unroll")                                                    \
        for (int mi = 0; mi < 2; mi++)                                       \
          acc[mi][nj] = __builtin_amdgcn_mfma_f32_16x16x32_f16(av[mi][kk], bv[nj][kk], acc[mi][nj], 0, 0, 0); \
  } while (0)

#define VM4  asm volatile("s_waitcnt vmcnt(4)" ::: "memory")
#define VM0  asm volatile("s_waitcnt vmcnt(0)" ::: "memory")
#define BAR  __builtin_amdgcn_s_barrier()

  STAGE(0, 0); KEYS4(0);
  STAGE(1, 1); KEYS4(1); VM4; BAR; COMPUTE(0); BAR;
  STAGE(0, 2); KEYS4(2); VM4; BAR; COMPUTE(1); BAR;
  STAGE(1, 3); KEYS4(3); VM4; BAR; COMPUTE(0); BAR;
  STAGE(0, 4); KEYS4(4); VM4; BAR; COMPUTE(1); BAR;
  STAGE(1, 5); KEYS4(5); VM4; BAR; COMPUTE(0); BAR;
  STAGE(0, 6); KEYS4(6); VM4; BAR; COMPUTE(1); BAR;
  STAGE(1, 7); KEYS4(7); VM4; BAR; COMPUTE(0); BAR;
               VM0; BAR; COMPUTE(1);
#undef STAGE
#undef COMPUTE
#undef GLDS
#undef VM4
#undef VM0
#undef BAR
#undef KEYS4
  __syncthreads();

  // epilogue partial arrays overlaid on LDS: [2 wc][128 rows]
  uint32_t* pKey = (uint32_t*)lds;
  float*    pD   = (float*)(pKey + 256);
  float*    pM   = pD + 256;

  // batched uniforms
  float ngv4[4];
  int cg4[4], cc4[4];
#pragma unroll
  for (int nj = 0; nj < 4; nj++) {
    const int c = c0 + wc * 64 + nj * 16 + lane16;
    ngv4[nj] = ngd[c];
    cg4[nj] = c >> NIMG_SHIFT;
    cc4[nj] = c;
  }

#pragma unroll
  for (int mi = 0; mi < 2; mi++) {
    const int rbase = r0 + wr * 32 + mi * 16 + g16 * 4;
    const float4 nq4 = *(const float4*)(nqd + rbase);
    const float4 ps4 = *(const float4*)(psd + rbase);
#pragma unroll
    for (int q = 0; q < 4; q++) {
      const int rr = wr * 32 + mi * 16 + g16 * 4 + q;
      const int rg = (rbase + q) >> NIMG_SHIFT;
      const float nqv = ((const float*)&nq4)[q];
      const float thr = ((const float*)&ps4)[q] + 1e-4f;
      uint32_t bKey = 0u, bC = 0xFFFFFFFFu, mC = 0xFFFFFFFFu;
      float bD = 0.0f, mD = INFINITY;
#pragma unroll
      for (int nj = 0; nj < 4; nj++) {   // c ascending: strict compares keep first
        const float dv = fmaxf(nqv + ngv4[nj] - 2.0f * acc[mi][nj][q], 1e-8f);
        const float dn = (cg4[nj] == rg) ? 1e25f : dv;
        if (dn < mD) { mD = dn; mC = (uint32_t)cc4[nj]; }
        const uint32_t key = (dn < thr) ? keys[mi * 16 + q * 4 + nj] : 0u;
        if (key > bKey) { bKey = key; bC = (uint32_t)cc4[nj]; bD = dn; }
      }
#pragma unroll
      for (int off = 8; off >= 1; off >>= 1) {
        const uint32_t kO = __shfl_xor(bKey, off, 64);
        const uint32_t cO = __shfl_xor(bC, off, 64);
        const float dO = __shfl_xor(bD, off, 64);
        if (kO > bKey || (kO == bKey && cO < bC)) { bKey = kO; bC = cO; bD = dO; }
        const float mdO = __shfl_xor(mD, off, 64);
        const uint32_t mcO = __shfl_xor(mC, off, 64);
        if (mdO < mD || (mdO == mD && mcO < mC)) { mD = mdO; mC = mcO; }
      }
      if (lane16 == 0) {
        const int idx = wc * 128 + rr;
        pKey[idx] = bKey; pD[idx] = bD; pM[idx] = mD;
      }
    }
  }
  __syncthreads();
  if (t < 128) {
    // combine column halves; ties resolve to half 0 (smaller columns) = first index
    const uint32_t k0 = pKey[t], k1 = pKey[t + 128];
    const float d0 = pD[t], d1 = pD[t + 128];
    const uint32_t bk = (k1 > k0) ? k1 : k0;
    const float bd = (k1 > k0) ? d1 : d0;
    const float m0 = pM[t], m1 = pM[t + 128];
    const float md = (m1 < m0) ? m1 : m0;
    const int p = blockIdx.x * B + (r0 + t);   // [chunk][row]: coalesced
    bKeyd[p] = bk; bDnd[p] = bd; mDnd[p] = md;
  }
}

// ---------------- Kernel 4a: per-row chunk combine + softplus, block partial --
__global__ __launch_bounds__(256) void fin1_k() {
  __shared__ float red[8];
  const int t = threadIdx.x;
  const int lrow = t >> 5;              // 0..7 rows per block
  const int ch = t & 31;                // chunk index (NCH=32)
  const int r = blockIdx.x * 8 + lrow;
  const int p = ch * B + r;             // [chunk][row]
  uint32_t bk = bKeyd[p];
  uint32_t bch = (uint32_t)ch;
  float bd = bDnd[p];
  float md = mDnd[p];
  uint32_t mch = (uint32_t)ch;
#pragma unroll
  for (int off = 16; off >= 1; off >>= 1) {
    const uint32_t kO = __shfl_xor(bk, off, 64);
    const uint32_t cO = __shfl_xor(bch, off, 64);
    const float dO = __shfl_xor(bd, off, 64);
    if (kO > bk || (kO == bk && cO < bch)) { bk = kO; bch = cO; bd = dO; }
    const float mO = __shfl_xor(md, off, 64);
    const uint32_t mcO = __shfl_xor(mch, off, 64);
    if (mO < md || (mO == md && mcO < mch)) { md = mO; mch = mcO; }
  }
  if (ch == 0) {
    const float dn = (bk != 0u) ? bd : md;
    const float x = 1e-4f + spd[r] - sqrtf(dn);
    red[lrow] = fmaxf(x, 0.0f) + log1pf(expf(-fabsf(x)));
  }
  __syncthreads();
  if (t == 0) {
    float s = 0.0f;
#pragma unroll
    for (int i = 0; i < 8; i++) s += red[i];
    partd[blockIdx.x] = s;
  }
}

// ---------------- Kernel 4b: sum 512 partials, mean ----------------
__global__ __launch_bounds__(256) void fin2_k(float* __restrict__ out) {
  __shared__ float red[256];
  const int t = threadIdx.x;
  red[t] = partd[t] + partd[t + 256];
  __syncthreads();
#pragma unroll
  for (int s = 128; s; s >>= 1) {
    if (t < s) red[t] += red[t + s];
    __syncthreads();
  }
  if (t == 0) out[0] = red[0] * (1.0f / (float)B);
}

extern "C" void kernel_launch(void* const* d_in, const int* in_sizes, int n_in,
                              void* d_out, int out_size, void* d_ws, size_t ws_size,
                              hipStream_t stream) {
  (void)in_sizes; (void)n_in; (void)out_size; (void)d_ws; (void)ws_size;
  const float* Q = (const float*)d_in[0];
  const float* G = (const float*)d_in[1];
  float* out = (float*)d_out;

  uint32_t kp0, kp1, kn0, kn1;
  tf2x32(0u, 42u, 0u, 0u, kp0, kp1);
  tf2x32(0u, 42u, 0u, 1u, kn0, kn1);

  hipLaunchKernelGGL(cvp_k, dim3(B / 8), dim3(256), 0, stream, Q, G, kp0, kp1);
  hipLaunchKernelGGL(neg_k, dim3(B / BN, B / BM), dim3(512), 0, stream, kn0, kn1);
  hipLaunchKernelGGL(fin1_k, dim3(B / 8), dim3(256), 0, stream);
  hipLaunchKernelGGL(fin2_k, dim3(1), dim3(256), 0, stream, out);
}